// Round 12
// baseline (5623.252 us; speedup 1.0000x reference)
//
#include <hip/hip_runtime.h>
#include <math.h>

#define TSEQ 500
#define BQ   200
#define DIN  300
#define H1   256
#define H2   300
#define K1   556          // both layers: 256 state/o1 + 300 x/h2
#define KP   576          // 18 MFMA k-steps of 32
#define H1P  256          // h1 row stride (ushorts)
#define H2P  304          // h2 row stride (300 + 4 zero pad)
#define BQC  25           // batches per chunk (8 chunks * 25 = 200)
#define LB1  4            // L1 blocks per chunk (64 units each)
#define LB2  5            // L2 blocks per chunk (64 units, last half-pad)
#define LBT  9
#define NBLK 72           // 8 chunks * 9 blocks

#define H1SLOT (BQ*H1P)   // 51200 ushorts per slot (triple-buffered)
#define H2SLOT (BQ*H2P)   // 60800

// ws byte offsets (16B aligned)
#define WS_H1   0         // ushort [3][200][256] = 307200 B
#define WS_H2   307200    // ushort [3][200][304] = 364800 B
#define WS_C1   672000    // float [256][200] (fallback path only)
#define WS_C2   876800    // float [320][200] (fallback path only)
#define WS_FLG  1132800   // 8 chunks * 512 B: int[0..71] per-wave flags, int[80..84] rdflg
#define WS_MSET 1136896

typedef __attribute__((ext_vector_type(8))) short short8;
typedef __attribute__((ext_vector_type(4))) float f32x4;
typedef unsigned long long u64;

__device__ __forceinline__ float sigf(float v){ return 1.0f/(1.0f+__expf(-v)); }
__device__ __forceinline__ float tanhf_(float v){
    v = fminf(15.0f, fmaxf(-15.0f, v));
    float e = __expf(2.0f*v);
    return (e-1.0f)/(e+1.0f);
}
__device__ __forceinline__ unsigned short f2bf(float f){   // RNE, finite inputs
    unsigned int xx = __builtin_bit_cast(unsigned int, f);
    xx = (xx + 0x7FFFu + ((xx>>16)&1u)) >> 16;
    return (unsigned short)xx;
}
// SYSTEM scope (sc0 sc1): bypass L1/L2, serviced at the MALL coherence point.
__device__ __forceinline__ u64 ld8_sys(const void* p){
    return __hip_atomic_load((const u64*)p, __ATOMIC_RELAXED, __HIP_MEMORY_SCOPE_SYSTEM);
}
// RETURNING swap as state publish: vmcnt retires only when the MALL executed
// the RMW (plain sc0sc1 stores are posted -- round-4 race). Proven r5-r9.
__device__ __forceinline__ void pub8(u64* p, u64 v){
    u64 old = __hip_atomic_exchange(p, v, __ATOMIC_RELAXED, __HIP_MEMORY_SCOPE_SYSTEM);
    asm volatile("" :: "v"(old));
}
__device__ __forceinline__ int ldflag(const int* p){
    return __hip_atomic_load(p, __ATOMIC_RELAXED, __HIP_MEMORY_SCOPE_SYSTEM);
}
__device__ __forceinline__ void stflag(int* p, int v){
    __hip_atomic_store(p, v, __ATOMIC_RELAXED, __HIP_MEMORY_SCOPE_SYSTEM);
}

union U16B { short8 s8; u64 u[2]; unsigned short us[8]; };
union U8B  { u64 u; unsigned short us[4]; };

// ==== Sync protocol (per-wave flags; r9 MALL semantics) =====================
// Producer wave: returning-swaps -> s_waitcnt vmcnt(0) (swaps APPLIED) ->
// posted flag wflg[block*8+wave] = it+1. Consumer lane: poll its one needed
// flag >= it -> compiler fence -> sys loads (HW order via control dependency).
// Flag index == k-chunk index kc (L1 waves: 0..31, L2 waves: 32..71).
// WAR: triple-buffered slots + flag transitivity (same-layer); L1->publish
// waits rdflg (L2 staging-done, set after B1) with 1-iter slack.
// Deadlock audit: every polled flag has an unconditional producer (inactive
// iters still flag); L1 flags BEFORE its rdflg tail-poll -> no L1<->L2 cycle.
// ============================================================================

__global__ __launch_bounds__(512, 1)
void lstm_mfma(const float* __restrict__ x, const int* __restrict__ lengths,
               const float* __restrict__ Wih1, const float* __restrict__ Whh1,
               const float* __restrict__ bih1, const float* __restrict__ bhh1,
               const float* __restrict__ Wih2, const float* __restrict__ Whh2,
               const float* __restrict__ bih2, const float* __restrict__ bhh2,
               float* __restrict__ out, char* __restrict__ wsb,
               int it_begin, int it_end, int coop)
{
    __shared__ unsigned short Al[32*KP];   // 36864 B  [batch][k] bf16, swizzled
    __shared__ float gl[256*33];           // 33792 B  gate exchange (wave-local)
    __shared__ float bias[256];
    __shared__ int lenl[32];

    const int tid = threadIdx.x;
    const int bid = blockIdx.x;
    const int mc  = bid & 7;               // batch chunk
    const int lbi = bid >> 3;              // 0..8: 0..3 = L1, 4..8 = L2
    const bool l1 = lbi < LB1;
    const int ub  = (l1 ? lbi : lbi - LB1) * 64;   // unit base
    const int Hl  = l1 ? H1 : H2;

    unsigned short* h1s = (unsigned short*)(wsb + WS_H1);
    unsigned short* h2s = (unsigned short*)(wsb + WS_H2);
    float* c1 = (float*)(wsb + WS_C1);
    float* c2 = (float*)(wsb + WS_C2);
    int* wflg  = (int*)(wsb + WS_FLG + mc*512);    // [0..71] per-wave flags
    int* rdflg = wflg + 80;                        // [0..4] L2 staging-done

    const int wave = tid >> 6, lane = tid & 63;
    const int fr = lane & 15, fg = lane >> 4;
    const int sw = fr & 7;

    // ---- weights -> VGPR (144), once. Wave w owns gate rows 32w..32w+31
    //      (= units 8w..8w+7, gate-interleaved r=4u+g). k<256 = state part.
    short8 wreg[2][18];
    #pragma unroll
    for (int rt = 0; rt < 2; ++rt){
        const int row = wave*32 + rt*16 + fr;
        const int u = row >> 2, g = row & 3;
        const int unit = ub + u;
        const bool vr = unit < Hl;
        const long grow = (long)g*Hl + unit;
        #pragma unroll
        for (int ks = 0; ks < 18; ++ks){
            unsigned short v8[8];
            #pragma unroll
            for (int j = 0; j < 8; ++j){
                int k = ks*32 + fg*8 + j;
                float v = 0.0f;
                if (vr && k < K1){
                    if (l1) v = (k < H1) ? Whh1[grow*H1 + k] : Wih1[grow*DIN + (k - H1)];
                    else    v = (k < H1) ? Wih2[grow*H1 + k] : Whh2[grow*H2 + (k - H1)];
                }
                v8[j] = f2bf(v);
            }
            wreg[rt][ks] = *(short8*)v8;
        }
    }
    if (tid < 256){
        int u = tid >> 2, g = tid & 3, unit = ub + u;
        bias[tid] = (unit < Hl)
            ? ((l1?bih1:bih2)[g*Hl+unit] + (l1?bhh1:bhh2)[g*Hl+unit]) : 0.0f;
    }
    if (tid < 32) lenl[tid] = (tid < BQC) ? lengths[mc*BQC + tid] : 0;

    const unsigned short* arow0 = &Al[fr*KP];
    const unsigned short* arow1 = &Al[(16+fr)*KP];
    const int bg_e = mc*BQC + lane;        // epilogue batch (lane<BQC valid)
    const int unit8 = ub + wave*8;         // this wave's 8 published units

    float creg[8] = {0.f,0.f,0.f,0.f,0.f,0.f,0.f,0.f};
    if (!coop && lane < BQC){
        float* cs = l1 ? c1 : c2;
        #pragma unroll
        for (int j = 0; j < 8; ++j) creg[j] = cs[(unit8 + j)*BQ + bg_e];
    }

    __syncthreads();

    for (int it = it_begin; it < it_end; ++it){
        const bool active = l1 ? (it < TSEQ) : (it >= 1);
        const int t = l1 ? it : it - 1;

        if (active){
            if (l1){
                // ---- stage x panel (k 256..575), cached loads ----
                #pragma unroll
                for (int i = 0; i < 3; ++i){
                    int e = tid + i*512;
                    if (e < 1280){
                        int bl = e/40, kcx = 32 + e - (e/40)*40;     // kcx 32..71
                        U16B v; v.u[0] = 0; v.u[1] = 0;
                        if (bl < BQC && kcx <= 69){
                            int bg = mc*BQC + bl;
                            const float* xp = x + ((size_t)bg*TSEQ + t)*DIN + (kcx*8 - 256);
                            float4 f0 = *(const float4*)xp;
                            v.us[0]=f2bf(f0.x); v.us[1]=f2bf(f0.y); v.us[2]=f2bf(f0.z); v.us[3]=f2bf(f0.w);
                            if (kcx <= 68){
                                float4 f1 = *(const float4*)(xp + 4);
                                v.us[4]=f2bf(f1.x); v.us[5]=f2bf(f1.y); v.us[6]=f2bf(f1.z); v.us[7]=f2bf(f1.w);
                            }
                        }
                        *(short8*)&Al[bl*KP + ((kcx ^ (bl&7))<<3)] = v.s8;
                    }
                }
                // ---- per-lane producer-wave flag poll, then state loads ----
                const int kc0 = tid & 31;              // flag index == kc0
                if (coop && it > it_begin){
                    const int* fp = wflg + kc0;
                    while (ldflag(fp) < it) __builtin_amdgcn_s_sleep(1);
                    asm volatile("" ::: "memory");     // no load hoist above poll
                }
                const unsigned short* h1p = h1s + (it%3)*H1SLOT;
                const int bl0 = tid >> 5, bl1 = bl0 + 16;
                u64 a0=0, a1=0, a2=0, a3=0;
                {
                    const u64* p0 = (const u64*)(h1p + (size_t)(mc*BQC + bl0)*H1P + kc0*8);
                    a0 = ld8_sys(p0); a1 = ld8_sys(p0 + 1);    // bl0 < 16 < BQC
                }
                if (bl1 < BQC){
                    const u64* p2 = (const u64*)(h1p + (size_t)(mc*BQC + bl1)*H1P + kc0*8);
                    a2 = ld8_sys(p2); a3 = ld8_sys(p2 + 1);
                }
                U16B w0; w0.u[0] = a0; w0.u[1] = a1;
                U16B w1; w1.u[0] = a2; w1.u[1] = a3;
                *(short8*)&Al[bl0*KP + ((kc0 ^ (bl0&7))<<3)] = w0.s8;
                *(short8*)&Al[bl1*KP + ((kc0 ^ (bl1&7))<<3)] = w1.s8;
            } else {
                // ---- L2: per-entry flag poll (flag idx == kc), then loads ----
                const unsigned short* h1p = h1s + (it%3)*H1SLOT;        // o1 source
                const unsigned short* h2p = h2s + ((it+2)%3)*H2SLOT;    // h2(it-1)
                const u64* pp[5]; bool qa[5], qb[5], fq[5]; const int* fpp[5];
                u64 va[5], vb[5];
                #pragma unroll
                for (int i = 0; i < 5; ++i){
                    const int e = tid + i*512;
                    const int bl = e/72, kc = e - (e/72)*72;
                    pp[i] = nullptr; fpp[i] = wflg; qa[i]=false; qb[i]=false; fq[i]=false;
                    va[i] = 0; vb[i] = 0;
                    if (e < 2304 && bl < BQC && kc < 70){
                        const int bg = mc*BQC + bl;
                        if (kc < 32){                          // o1 = masked h1
                            if (t < lenl[bl]){
                                pp[i] = (const u64*)(h1p + (size_t)bg*H1P + kc*8);
                                qa[i] = true; qb[i] = true; fq[i] = true; fpp[i] = wflg + kc;
                            }
                        } else {                               // h2 (kc=69: 2nd half pad)
                            pp[i] = (const u64*)(h2p + (size_t)bg*H2P + (kc*8 - 256));
                            qa[i] = true; qb[i] = (kc < 69); fq[i] = true; fpp[i] = wflg + kc;
                        }
                    }
                }
                if (coop){
                    bool pend = fq[0]|fq[1]|fq[2]|fq[3]|fq[4];
                    while (pend){
                        pend = false;
                        #pragma unroll
                        for (int i = 0; i < 5; ++i)
                            if (fq[i]){
                                if (ldflag(fpp[i]) >= it) fq[i] = false; else pend = true;
                            }
                        if (pend) __builtin_amdgcn_s_sleep(1);
                    }
                    asm volatile("" ::: "memory");     // no load hoist above poll
                }
                #pragma unroll
                for (int i = 0; i < 5; ++i){
                    if (qa[i]) va[i] = ld8_sys(pp[i]);
                    if (qb[i]) vb[i] = ld8_sys(pp[i] + 1);
                }
                #pragma unroll
                for (int i = 0; i < 5; ++i){
                    const int e = tid + i*512;
                    if (e < 2304){
                        const int bl = e/72, kc = e - (e/72)*72;
                        U16B v; v.u[0] = va[i]; v.u[1] = vb[i];
                        *(short8*)&Al[bl*KP + ((kc ^ (bl&7))<<3)] = v.s8;
                    }
                }
            }
        }
        __syncthreads();   // B1: staging complete
        if (!l1 && coop && tid == 0)       // L2 staging-done (posted: progress only)
            stflag(&rdflg[lbi - LB1], it + 1);

        if (active){
            // ---- 18 k-step MFMA: 2 row-tiles x 2 batch-tiles, weights in VGPR ----
            f32x4 a00={0.f,0.f,0.f,0.f}, a01={0.f,0.f,0.f,0.f};
            f32x4 a10={0.f,0.f,0.f,0.f}, a11={0.f,0.f,0.f,0.f};
            #pragma unroll
            for (int ks = 0; ks < 18; ++ks){
                const int off = ((ks*4 + fg) ^ sw) << 3;
                short8 b0 = *(const short8*)(arow0 + off);
                short8 b1 = *(const short8*)(arow1 + off);
                a00 = __builtin_amdgcn_mfma_f32_16x16x32_bf16(wreg[0][ks], b0, a00, 0, 0, 0);
                a01 = __builtin_amdgcn_mfma_f32_16x16x32_bf16(wreg[0][ks], b1, a01, 0, 0, 0);
                a10 = __builtin_amdgcn_mfma_f32_16x16x32_bf16(wreg[1][ks], b0, a10, 0, 0, 0);
                a11 = __builtin_amdgcn_mfma_f32_16x16x32_bf16(wreg[1][ks], b1, a11, 0, 0, 0);
            }
            // wave-local gate exchange (wave w owns rows 32w..32w+31)
            const int r0 = wave*32 + fg*4;
            #pragma unroll
            for (int q = 0; q < 4; ++q){
                gl[(r0+q)*33 + fr]         = a00[q];
                gl[(r0+q)*33 + 16 + fr]    = a01[q];
                gl[(r0+16+q)*33 + fr]      = a10[q];
                gl[(r0+16+q)*33 + 16 + fr] = a11[q];
            }
            // ---- epilogue: lane b -> units unit8..unit8+7, batch b ----
            if (lane < BQC){
                float hv[8]; unsigned short hb[8];
                #pragma unroll
                for (int j = 0; j < 8; ++j){
                    const int r = wave*32 + 4*j;
                    float gi = gl[(r+0)*33 + lane] + bias[r+0];
                    float gf = gl[(r+1)*33 + lane] + bias[r+1];
                    float gg = gl[(r+2)*33 + lane] + bias[r+2];
                    float go = gl[(r+3)*33 + lane] + bias[r+3];
                    float iv = sigf(gi), fv = sigf(gf), cv = tanhf_(gg), ov = sigf(go);
                    float c = fmaf(fv, creg[j], iv*cv); creg[j] = c;
                    hv[j] = ov * tanhf_(c);
                    hb[j] = f2bf(hv[j]);
                }
                U8B p0, p1;
                p0.us[0]=hb[0]; p0.us[1]=hb[1]; p0.us[2]=hb[2]; p0.us[3]=hb[3];
                p1.us[0]=hb[4]; p1.us[1]=hb[5]; p1.us[2]=hb[6]; p1.us[3]=hb[7];
                if (l1){
                    u64* dp = (u64*)&h1s[((it+1)%3)*H1SLOT + (size_t)bg_e*H1P + unit8];
                    pub8(dp, p0.u); pub8(dp + 1, p1.u);
                    if (it == lenl[lane] - 1){           // h_value (fp32 h)
                        float* hp = out + 30000000 + (size_t)bg_e*H1 + unit8;
                        float4 q0; q0.x=hv[0]; q0.y=hv[1]; q0.z=hv[2]; q0.w=hv[3];
                        float4 q1; q1.x=hv[4]; q1.y=hv[5]; q1.z=hv[6]; q1.w=hv[7];
                        *(float4*)hp = q0; *(float4*)(hp + 4) = q1;
                    }
                } else {
                    u64* dp = (u64*)&h2s[(it%3)*H2SLOT + (size_t)bg_e*H2P + unit8];
                    if (unit8 < H2)     pub8(dp, p0.u);
                    if (unit8 + 4 < H2) pub8(dp + 1, p1.u);
                    if (unit8 < H2){
                        float* op = out + (size_t)bg_e*150000 + (size_t)t*300 + unit8;
                        float4 q0; q0.x=hv[0]; q0.y=hv[1]; q0.z=hv[2]; q0.w=hv[3];
                        *(float4*)op = q0;
                        if (unit8 + 4 < H2){
                            float4 q1; q1.x=hv[4]; q1.y=hv[5]; q1.z=hv[6]; q1.w=hv[7];
                            *(float4*)(op + 4) = q1;
                        }
                    }
                }
            }
        }

        // ---- per-wave flag: own swaps APPLIED (vmcnt 0) -> posted flag.
        //      Unconditional (inactive iters flag too: slot zeros are valid).
        if (coop){
            asm volatile("s_waitcnt vmcnt(0)" ::: "memory");
            __builtin_amdgcn_sched_barrier(0);
            if (lane == 0) stflag(&wflg[lbi*8 + wave], it + 1);
        }
        // ---- L1 tail: L2 staging of iter it-1 done before next-iter publish
        //      overwrites the slot L2 read at it-2 (1-iter slack, off-path) ----
        if (l1 && coop && it > 0 && it < TSEQ-1 && tid < LB2){
            while (ldflag(&rdflg[tid]) < it) __builtin_amdgcn_s_sleep(1);
        }
        // ---- B2 (raw, LDS-only drain): publish/flag RTTs overlap next iter ----
        asm volatile("s_waitcnt lgkmcnt(0)" ::: "memory");
        __builtin_amdgcn_sched_barrier(0);
        __builtin_amdgcn_s_barrier();
        __builtin_amdgcn_sched_barrier(0);
    }

    if (!coop && lane < BQC){
        float* cs = l1 ? c1 : c2;
        #pragma unroll
        for (int j = 0; j < 8; ++j) cs[(unit8 + j)*BQ + bg_e] = creg[j];
    }
}

extern "C" void kernel_launch(void* const* d_in, const int* in_sizes, int n_in,
                              void* d_out, int out_size, void* d_ws, size_t ws_size,
                              hipStream_t stream) {
    const float* x    = (const float*)d_in[0];
    const int*   lens = (const int*)  d_in[1];
    const float* Wih1 = (const float*)d_in[2];
    const float* Whh1 = (const float*)d_in[3];
    const float* bih1 = (const float*)d_in[4];
    const float* bhh1 = (const float*)d_in[5];
    const float* Wih2 = (const float*)d_in[6];
    const float* Whh2 = (const float*)d_in[7];
    const float* bih2 = (const float*)d_in[8];
    const float* bhh2 = (const float*)d_in[9];
    float* out = (float*)d_out;
    char*  ws  = (char*)d_ws;

    // zero state slots, flags, fallback c -- every call (deterministic)
    hipMemsetAsync(d_ws, 0, (size_t)WS_MSET, stream);

    int ib = 0, ie = TSEQ + 1, coop = 1;
    void* args[] = {(void*)&x, (void*)&lens, (void*)&Wih1, (void*)&Whh1, (void*)&bih1, (void*)&bhh1,
                    (void*)&Wih2, (void*)&Whh2, (void*)&bih2, (void*)&bhh2,
                    (void*)&out, (void*)&ws, (void*)&ib, (void*)&ie, (void*)&coop};
    hipError_t err = hipLaunchCooperativeKernel((const void*)lstm_mfma, dim3(NBLK), dim3(512),
                                                args, 0, stream);
    if (err != hipSuccess) {
        (void)hipGetLastError();   // fall back: one launch per iteration (state in ws)
        for (int it = 0; it <= TSEQ; ++it) {
            hipLaunchKernelGGL(lstm_mfma, dim3(NBLK), dim3(512), 0, stream,
                               x, lens, Wih1, Whh1, bih1, bhh1, Wih2, Whh2, bih2, bhh2,
                               out, ws, it, it + 1, 0);
        }
    }
}

// Round 13
// 2774.511 us; speedup vs baseline: 2.0268x; 2.0268x over previous
//
#include <hip/hip_runtime.h>
#include <math.h>

#define TSEQ 500
#define BQ   200
#define DIN  300
#define H1   256
#define H2   300
#define K1   556          // both layers: 256 recurrent/o1 + 300 x/h2
#define KP   576          // 18 MFMA k-steps of 32; k 0..255 = state, 256..555 = x|h2
#define H1P  256          // h1 row stride (ushorts)
#define H2P  304          // h2 row stride (300 + 4 zero pad)
#define BQC  25           // batches per chunk (8 chunks * 25 = 200)
#define LB1  8            // L1 blocks per chunk (32 units each)
#define LBT  18           // blocks per chunk (8 L1 + 10 L2)
#define NBLK 144          // 8 chunks * 18

#define H1SLOT (BQ*H1P)   // 51200 ushorts per slot (triple-buffered)
#define H2SLOT (BQ*H2P)   // 60800

// ws byte offsets (16B aligned)
#define WS_H1   0         // ushort [3][200][256] = 307200 B
#define WS_H2   307200    // ushort [3][200][304] = 364800 B
#define WS_C1   672000    // float [256][200] (fallback path only)
#define WS_C2   876800    // float [320][200] (fallback path only)
#define WS_FLG  1132800   // 8 chunks * 128 B (18 int flags)
#define WS_MSET 1133824

typedef __attribute__((ext_vector_type(8))) short short8;
typedef __attribute__((ext_vector_type(4))) float f32x4;
typedef unsigned long long u64;

__device__ __forceinline__ float sigf(float v){ return 1.0f/(1.0f+__expf(-v)); }
__device__ __forceinline__ float tanhf_(float v){
    v = fminf(15.0f, fmaxf(-15.0f, v));
    float e = __expf(2.0f*v);
    return (e-1.0f)/(e+1.0f);
}
__device__ __forceinline__ unsigned short f2bf(float f){   // RNE, finite inputs
    unsigned int xx = __builtin_bit_cast(unsigned int, f);
    xx = (xx + 0x7FFFu + ((xx>>16)&1u)) >> 16;
    return (unsigned short)xx;
}
// SYSTEM scope (sc0 sc1): bypass L1/L2, serviced at the MALL coherence point.
// Proven stable (rounds 5-9). NO cache flushes anywhere.
__device__ __forceinline__ u64 ld8_sys(const void* p){
    return __hip_atomic_load((const u64*)p, __ATOMIC_RELAXED, __HIP_MEMORY_SCOPE_SYSTEM);
}
// RETURNING swap as state publish: vmcnt retires only when the MALL executed
// the RMW (plain sc0sc1 stores are posted -- round-4 race). asm-consume forces
// the returning variant.
__device__ __forceinline__ void pub8(u64* p, u64 v){
    u64 old = __hip_atomic_exchange(p, v, __ATOMIC_RELAXED, __HIP_MEMORY_SCOPE_SYSTEM);
    asm volatile("" :: "v"(old));
}

union U16B { short8 s8; u64 u[2]; unsigned short us[8]; };
union U8B  { u64 u; unsigned short us[4]; };

// ==== Sync protocol (r9 semantics + early flag + staggered polls) ===========
// Producer block: each wave (epilogue publishes done) executes s_waitcnt
// vmcnt(0) (its returning swaps are APPLIED at the MALL), bumps an LDS
// arrival counter; the LAST-draining wave posts the block flag = it+1.
// Transitivity: flag visible => all 8 waves' swaps applied. Flags monotonic
// (prior flag store drained at its wave's next __syncthreads before the next
// flag can be issued). Then a RAW s_barrier (lgkmcnt only) guards the Al
// LDS WAR -- publish RTTs overlap the next iteration's staging.
// Consumer: 4 staggered lanes per flag (72 lanes, 18 unique lines -- NARROW;
// r11/r12 lesson: wide scattered polls choke the MALL) poll flg[fi] >= tgt,
// then full B0 barrier, then sc-bypass state loads (control-dependent).
// WAR edges (triple buffer + 1-iter L2 slack) identical to r9.
// ============================================================================

__global__ __launch_bounds__(512, 2)
void lstm_mfma(const float* __restrict__ x, const int* __restrict__ lengths,
               const float* __restrict__ Wih1, const float* __restrict__ Whh1,
               const float* __restrict__ bih1, const float* __restrict__ bhh1,
               const float* __restrict__ Wih2, const float* __restrict__ Whh2,
               const float* __restrict__ bih2, const float* __restrict__ bhh2,
               float* __restrict__ out, char* __restrict__ wsb,
               int it_begin, int it_end, int coop)
{
    __shared__ unsigned short Al[32*KP];   // [batch][k] bf16, swizzled
    __shared__ float gl[128*33];           // gate exchange (wave-local rows)
    __shared__ float bias[128];
    __shared__ int lenl[32];
    __shared__ unsigned arrc;              // monotonic wave-arrival counter

    const int tid = threadIdx.x;
    const int bid = blockIdx.x;
    const int mc  = bid & 7;               // batch chunk
    const int lbi = bid >> 3;              // 0..17 within chunk
    const bool l1 = lbi < LB1;
    const int ub  = (l1 ? lbi : lbi - LB1) * 32;   // unit base
    const int Hl  = l1 ? H1 : H2;

    unsigned short* h1s = (unsigned short*)(wsb + WS_H1);
    unsigned short* h2s = (unsigned short*)(wsb + WS_H2);
    float* c1 = (float*)(wsb + WS_C1);
    float* c2 = (float*)(wsb + WS_C2);
    int* flg = (int*)(wsb + WS_FLG + mc*128);

    const int wave = tid >> 6, lane = tid & 63;
    const int fr = lane & 15, fg = lane >> 4;
    const int sw = fr & 7;

    // ---- weights -> VGPR, once. Row r = wave*16+fr = 4*u_local + gate.
    //      k layout: k<256 = recurrent/o1 part, k in [256,556) = x/h2 part.
    short8 wreg[18];
    {
        const int row = wave*16 + fr;
        const int u = row >> 2, g = row & 3;
        const int unit = ub + u;
        const bool vr = unit < Hl;                 // L2 block 9 pad units
        const long grow = (long)g*Hl + unit;
        #pragma unroll
        for (int ks = 0; ks < 18; ++ks){
            unsigned short v8[8];
            #pragma unroll
            for (int j = 0; j < 8; ++j){
                int k = ks*32 + fg*8 + j;
                float v = 0.0f;
                if (vr && k < K1){
                    if (l1) v = (k < H1) ? Whh1[grow*H1 + k] : Wih1[grow*DIN + (k - H1)];
                    else    v = (k < H1) ? Wih2[grow*H1 + k] : Whh2[grow*H2 + (k - H1)];
                }
                v8[j] = f2bf(v);
            }
            wreg[ks] = *(short8*)v8;
        }
    }
    if (tid < 128){
        int u = tid >> 2, g = tid & 3, unit = ub + u;
        bias[tid] = (unit < Hl)
            ? ((l1?bih1:bih2)[g*Hl+unit] + (l1?bhh1:bhh2)[g*Hl+unit]) : 0.0f;
    }
    if (tid < 32) lenl[tid] = (tid < BQC) ? lengths[mc*BQC + tid] : 0;
    if (tid == 0) arrc = 0;

    const unsigned short* arow0 = &Al[fr*KP];
    const unsigned short* arow1 = &Al[(16+fr)*KP];
    const int bg_e = mc*BQC + lane;        // epilogue batch (lane<BQC valid)
    const int unit4 = ub + wave*4;         // epilogue/publish unit group

    float creg[4] = {0.f, 0.f, 0.f, 0.f};
    if (!coop && lane < 32){
        float* cs = l1 ? c1 : c2;
        #pragma unroll
        for (int i2 = 0; i2 < 4; ++i2) creg[i2] = cs[(unit4 + i2)*BQ + bg_e];
    }

    __syncthreads();

    for (int it = it_begin; it < it_end; ++it){
        const bool active = l1 ? (it < TSEQ) : (it >= 1);
        const int t = l1 ? it : it - 1;

        // ---- L1: stage x panel (k 256..575) BEFORE the flag wait ----
        if (active && l1){
            #pragma unroll
            for (int i = 0; i < 3; ++i){
                int e = tid + i*512;
                if (e < 1280){
                    int bl = e/40, kcx = 32 + e - (e/40)*40;     // kcx 32..71
                    U16B v; v.u[0] = 0; v.u[1] = 0;
                    if (bl < BQC && kcx <= 69){
                        int bg = mc*BQC + bl;
                        const float* xp = x + ((size_t)bg*TSEQ + t)*DIN + (kcx*8 - 256);
                        float4 f0 = *(const float4*)xp;
                        v.us[0]=f2bf(f0.x); v.us[1]=f2bf(f0.y); v.us[2]=f2bf(f0.z); v.us[3]=f2bf(f0.w);
                        if (kcx <= 68){
                            float4 f1 = *(const float4*)(xp + 4);
                            v.us[4]=f2bf(f1.x); v.us[5]=f2bf(f1.y); v.us[6]=f2bf(f1.z); v.us[7]=f2bf(f1.w);
                        }
                    }
                    *(short8*)&Al[bl*KP + ((kcx ^ (bl&7))<<3)] = v.s8;
                }
            }
        }

        // ---- wait producer flags: 4 staggered lanes per flag (narrow set).
        // L1 needs L1 flags>=it, L2 flags>=it-1 (WAR slack); L2 needs all>=it.
        if (coop && it > it_begin && tid < 4*LBT){
            const int fi = tid >> 2;
            int tgt = l1 ? (fi < LB1 ? it : it - 1) : it;
            if (tgt > 0)
                while (__hip_atomic_load(&flg[fi], __ATOMIC_RELAXED,
                                         __HIP_MEMORY_SCOPE_SYSTEM) < tgt)
                    __builtin_amdgcn_s_sleep(1);
        }
        __syncthreads();   // B0: flags confirmed + x panel staged

        if (active){
            const unsigned short* h1p = h1s + (it % 3)*H1SLOT;       // h1(it-1)
            const unsigned short* h2p = h2s + ((it + 2) % 3)*H2SLOT; // h2(it-1)

            f32x4 acc0 = {0.f,0.f,0.f,0.f}, acc1 = {0.f,0.f,0.f,0.f};

            if (l1){
                // issue h1 state loads (MALL RTT)...
                u64 hv0, hv1, hv2, hv3;
                const int e0 = tid, e1 = tid + 512;
                const int bl0 = e0 >> 5, kc0 = e0 & 31;
                const int bl1 = e1 >> 5, kc1 = e1 & 31;
                if (bl0 < BQC){
                    const unsigned short* hp = h1p + (size_t)(mc*BQC + bl0)*H1P + kc0*8;
                    hv0 = ld8_sys(hp); hv1 = ld8_sys(hp + 4);
                } else { hv0 = 0; hv1 = 0; }
                if (bl1 < BQC){
                    const unsigned short* hp = h1p + (size_t)(mc*BQC + bl1)*H1P + kc1*8;
                    hv2 = ld8_sys(hp); hv3 = ld8_sys(hp + 4);
                } else { hv2 = 0; hv3 = 0; }
                // ...and hide their latency under the x-part MFMA (k-steps 8..17)
                #pragma unroll
                for (int ks = 8; ks < 18; ++ks){
                    const int off = ((ks*4 + fg) ^ sw) << 3;
                    short8 b0 = *(const short8*)(arow0 + off);
                    short8 b1 = *(const short8*)(arow1 + off);
                    acc0 = __builtin_amdgcn_mfma_f32_16x16x32_bf16(wreg[ks], b0, acc0, 0, 0, 0);
                    acc1 = __builtin_amdgcn_mfma_f32_16x16x32_bf16(wreg[ks], b1, acc1, 0, 0, 0);
                }
                U16B w0; w0.u[0] = hv0; w0.u[1] = hv1;
                U16B w1; w1.u[0] = hv2; w1.u[1] = hv3;
                *(short8*)&Al[bl0*KP + ((kc0 ^ (bl0&7))<<3)] = w0.s8;
                *(short8*)&Al[bl1*KP + ((kc1 ^ (bl1&7))<<3)] = w1.s8;
            } else {
                // L2: gather o1 (masked h1) + h2 into regs, then LDS-write
                u64 sv[10];
                #pragma unroll
                for (int i = 0; i < 5; ++i){
                    int e = tid + i*512;
                    u64 a = 0, b = 0;
                    if (e < 2304){
                        int bl = e/72, kc = e - (e/72)*72;
                        if (bl < BQC && kc < 70){
                            int bg = mc*BQC + bl;
                            if (kc < 32){                    // o1 = masked h1
                                if (t < lenl[bl]){
                                    const unsigned short* hp = h1p + (size_t)bg*H1P + kc*8;
                                    a = ld8_sys(hp); b = ld8_sys(hp + 4);
                                }
                            } else {                         // h2 (kc=69 hits zero pad)
                                const unsigned short* hp = h2p + (size_t)bg*H2P + (kc*8 - 256);
                                a = ld8_sys(hp); b = ld8_sys(hp + 4);
                            }
                        }
                    }
                    sv[2*i] = a; sv[2*i+1] = b;
                }
                #pragma unroll
                for (int i = 0; i < 5; ++i){
                    int e = tid + i*512;
                    if (e < 2304){
                        int bl = e/72, kc = e - (e/72)*72;
                        U16B v; v.u[0] = sv[2*i]; v.u[1] = sv[2*i+1];
                        *(short8*)&Al[bl*KP + ((kc ^ (bl&7))<<3)] = v.s8;
                    }
                }
            }
            __syncthreads();   // B1: state panel staged

            // ---- remaining MFMA (L1: k-steps 0..7; L2: all 18) ----
            if (l1){
                #pragma unroll
                for (int ks = 0; ks < 8; ++ks){
                    const int off = ((ks*4 + fg) ^ sw) << 3;
                    short8 b0 = *(const short8*)(arow0 + off);
                    short8 b1 = *(const short8*)(arow1 + off);
                    acc0 = __builtin_amdgcn_mfma_f32_16x16x32_bf16(wreg[ks], b0, acc0, 0, 0, 0);
                    acc1 = __builtin_amdgcn_mfma_f32_16x16x32_bf16(wreg[ks], b1, acc1, 0, 0, 0);
                }
            } else {
                #pragma unroll
                for (int ks = 0; ks < 18; ++ks){
                    const int off = ((ks*4 + fg) ^ sw) << 3;
                    short8 b0 = *(const short8*)(arow0 + off);
                    short8 b1 = *(const short8*)(arow1 + off);
                    acc0 = __builtin_amdgcn_mfma_f32_16x16x32_bf16(wreg[ks], b0, acc0, 0, 0, 0);
                    acc1 = __builtin_amdgcn_mfma_f32_16x16x32_bf16(wreg[ks], b1, acc1, 0, 0, 0);
                }
            }

            // wave-local gate exchange: wave w owns rows 16w..16w+15 entirely;
            // same-wave LDS ops are processed in order -> no barrier needed.
            const int gr = wave*16 + fg*4;
            #pragma unroll
            for (int q = 0; q < 4; ++q){
                gl[(gr+q)*33 + fr]      = acc0[q];
                gl[(gr+q)*33 + 16 + fr] = acc1[q];
            }

            // ---- epilogue: lane b -> units ub+4*wave+0..3, batch b ----
            if (lane < 32){
                float hv[4]; unsigned short hb[4];
                #pragma unroll
                for (int i2 = 0; i2 < 4; ++i2){
                    const int r = wave*16 + i2*4;
                    float gi = gl[(r+0)*33 + lane] + bias[r+0];
                    float gf = gl[(r+1)*33 + lane] + bias[r+1];
                    float gg = gl[(r+2)*33 + lane] + bias[r+2];
                    float go = gl[(r+3)*33 + lane] + bias[r+3];
                    float iv = sigf(gi), fv = sigf(gf), cv = tanhf_(gg), ov = sigf(go);
                    float c = fmaf(fv, creg[i2], iv*cv); creg[i2] = c;
                    hv[i2] = ov * tanhf_(c);
                    hb[i2] = f2bf(hv[i2]);
                }
                if (lane < BQC){
                    U8B pv; pv.us[0]=hb[0]; pv.us[1]=hb[1]; pv.us[2]=hb[2]; pv.us[3]=hb[3];
                    if (l1){
                        pub8((u64*)&h1s[((it+1)%3)*H1SLOT + (size_t)bg_e*H1P + unit4], pv.u);
                        if (it == lenl[lane] - 1){           // h_value (fp32 h)
                            float4 q; q.x=hv[0]; q.y=hv[1]; q.z=hv[2]; q.w=hv[3];
                            *(float4*)(out + 30000000 + (size_t)bg_e*H1 + unit4) = q;
                        }
                    } else if (unit4 < H2){
                        pub8((u64*)&h2s[(it%3)*H2SLOT + (size_t)bg_e*H2P + unit4], pv.u);
                        float4 q; q.x=hv[0]; q.y=hv[1]; q.z=hv[2]; q.w=hv[3];
                        *(float4*)(out + (size_t)bg_e*150000 + (size_t)t*300 + unit4) = q;
                    }
                }
            }
        } else {
            __syncthreads();   // B1 (inactive blocks keep barrier count aligned)
        }

        // ---- early flag: per-wave drain (swaps APPLIED) -> LDS arrival ->
        //      last-draining wave posts the block flag (no barrier wait).
        if (coop){
            asm volatile("s_waitcnt vmcnt(0)" ::: "memory");
            __builtin_amdgcn_sched_barrier(0);
            if (lane == 0){
                unsigned old = atomicAdd(&arrc, 1u);
                if (old == 8u*(unsigned)(it - it_begin + 1) - 1u)
                    __hip_atomic_store(&flg[lbi], it + 1, __ATOMIC_RELAXED,
                                       __HIP_MEMORY_SCOPE_SYSTEM);
            }
        }
        // ---- B2 (raw): Al/gl LDS WAR only; flag/publish RTTs overlap ahead ----
        asm volatile("s_waitcnt lgkmcnt(0)" ::: "memory");
        __builtin_amdgcn_sched_barrier(0);
        __builtin_amdgcn_s_barrier();
        __builtin_amdgcn_sched_barrier(0);
    }

    if (!coop && lane < 32){
        float* cs = l1 ? c1 : c2;
        #pragma unroll
        for (int i2 = 0; i2 < 4; ++i2) cs[(unit4 + i2)*BQ + bg_e] = creg[i2];
    }
}

extern "C" void kernel_launch(void* const* d_in, const int* in_sizes, int n_in,
                              void* d_out, int out_size, void* d_ws, size_t ws_size,
                              hipStream_t stream) {
    const float* x    = (const float*)d_in[0];
    const int*   lens = (const int*)  d_in[1];
    const float* Wih1 = (const float*)d_in[2];
    const float* Whh1 = (const float*)d_in[3];
    const float* bih1 = (const float*)d_in[4];
    const float* bhh1 = (const float*)d_in[5];
    const float* Wih2 = (const float*)d_in[6];
    const float* Whh2 = (const float*)d_in[7];
    const float* bih2 = (const float*)d_in[8];
    const float* bhh2 = (const float*)d_in[9];
    float* out = (float*)d_out;
    char*  ws  = (char*)d_ws;

    // zero state slots (incl. pad), flags, fallback c -- every call (deterministic)
    hipMemsetAsync(d_ws, 0, (size_t)WS_MSET, stream);

    int ib = 0, ie = TSEQ + 1, coop = 1;
    void* args[] = {(void*)&x, (void*)&lens, (void*)&Wih1, (void*)&Whh1, (void*)&bih1, (void*)&bhh1,
                    (void*)&Wih2, (void*)&Whh2, (void*)&bih2, (void*)&bhh2,
                    (void*)&out, (void*)&ws, (void*)&ib, (void*)&ie, (void*)&coop};
    hipError_t err = hipLaunchCooperativeKernel((const void*)lstm_mfma, dim3(NBLK), dim3(512),
                                                args, 0, stream);
    if (err != hipSuccess) {
        (void)hipGetLastError();   // fall back: one launch per iteration (state in ws)
        for (int it = 0; it <= TSEQ; ++it) {
            hipLaunchKernelGGL(lstm_mfma, dim3(NBLK), dim3(512), 0, stream,
                               x, lens, Wih1, Whh1, bih1, bhh1, Wih2, Whh2, bih2, bhh2,
                               out, ws, it, it + 1, 0);
        }
    }
}

// Round 14
// 2505.372 us; speedup vs baseline: 2.2445x; 1.1074x over previous
//
#include <hip/hip_runtime.h>
#include <math.h>

#define TSEQ 500
#define BQ   200
#define DIN  300
#define H1   256
#define H2   300
#define K1   556          // both layers: 256 recurrent/o1 + 300 x/h2
#define KP   576          // 18 MFMA k-steps of 32; k 0..255 = state, 256..555 = x|h2
#define H1P  256          // h1 row stride (ushorts)
#define H2P  304          // h2 row stride (300 + 4 zero pad)
#define BQC  25           // batches per chunk (8 chunks * 25 = 200)
#define LB1  8            // L1 blocks per chunk (32 units each)
#define LBT  18           // blocks per chunk (8 L1 + 10 L2)
#define NBLK 144          // 8 chunks * 18

#define H1SLOT (BQ*H1P)   // 51200 ushorts per slot (triple-buffered)
#define H2SLOT (BQ*H2P)   // 60800

// ws byte offsets (16B aligned)
#define WS_H1   0         // ushort [3][200][256] = 307200 B
#define WS_H2   307200    // ushort [3][200][304] = 364800 B
#define WS_C1   672000    // float [256][200] (fallback path only)
#define WS_C2   876800    // float [320][200] (fallback path only)
#define WS_FLG  1132800   // 8 chunks * 128 B (18 int flags)
#define WS_MSET 1133824

typedef __attribute__((ext_vector_type(8))) short short8;
typedef __attribute__((ext_vector_type(4))) float f32x4;
typedef unsigned long long u64;

__device__ __forceinline__ float sigf(float v){ return 1.0f/(1.0f+__expf(-v)); }
__device__ __forceinline__ float tanhf_(float v){
    v = fminf(15.0f, fmaxf(-15.0f, v));
    float e = __expf(2.0f*v);
    return (e-1.0f)/(e+1.0f);
}
__device__ __forceinline__ unsigned short f2bf(float f){   // RNE, finite inputs
    unsigned int xx = __builtin_bit_cast(unsigned int, f);
    xx = (xx + 0x7FFFu + ((xx>>16)&1u)) >> 16;
    return (unsigned short)xx;
}
// AGENT scope: cross-XCD coherent (atomics execute at the MALL coherence
// point -- m20: device-scope atomicAdd is cross-XCD correct). Same ordering
// semantics as the proven SYSTEM path (r5-r9), possibly cheaper per op.
__device__ __forceinline__ u64 ld8c(const void* p){
    return __hip_atomic_load((const u64*)p, __ATOMIC_RELAXED, __HIP_MEMORY_SCOPE_AGENT);
}
// RETURNING swap as state publish: vmcnt retires only when the coherence
// point executed the RMW (plain stores are posted -- round-4 race).
// asm-consume forces the returning variant.
__device__ __forceinline__ void pub8(u64* p, u64 v){
    u64 old = __hip_atomic_exchange(p, v, __ATOMIC_RELAXED, __HIP_MEMORY_SCOPE_AGENT);
    asm volatile("" :: "v"(old));
}
__device__ __forceinline__ int ldflag(const int* p){
    return __hip_atomic_load(p, __ATOMIC_RELAXED, __HIP_MEMORY_SCOPE_AGENT);
}
__device__ __forceinline__ void stflag(int* p, int v){
    __hip_atomic_store(p, v, __ATOMIC_RELAXED, __HIP_MEMORY_SCOPE_AGENT);
}

union U16B { short8 s8; u64 u[2]; unsigned short us[8]; };
union U8B  { u64 u; unsigned short us[4]; };

// ==== Sync protocol (r9 semantics + fused L1 poll/load) =====================
// Producer block: epilogue publishes (returning swaps) -> B2 full
// __syncthreads (vmcnt drained => swaps APPLIED) -> tid0 posts block flag
// = it+1 (posted; monotonic: same lane + same address).
// L1 consumer: per-lane FUSED poll+load -- each lane's two state granule
// pairs share one k-chunk kc0 = tid&31, whose producer block is kc0>>2, so
// the lane polls exactly ONE flag line (8 unique lines/block, 4 lanes each
// -- narrow, per r11-r13 lesson) then issues its loads immediately. The
// block-wide "all 8 producer flags >= it" guarantee (needed for the
// publish-WAR) is re-established at B1, which all lanes' polls precede.
// L1 WAR edge vs L2 o1-readers: 10 side lanes poll L2 flags >= it-1
// (1-iter slack, triple buffer), also ordered by B1 before any publish.
// L2 consumer: r9 structure unchanged (poll all 18 flags -> B0 -> loads);
// L2 trails L1 by one step, so its detect latency is pipelined slack.
// Deadlock audit: every flag posted unconditionally every iteration (B2 +
// flag store outside the `active` guard); dependency targets strictly
// decrease in t -> acyclic.
// ============================================================================

__global__ __launch_bounds__(512, 2)
void lstm_mfma(const float* __restrict__ x, const int* __restrict__ lengths,
               const float* __restrict__ Wih1, const float* __restrict__ Whh1,
               const float* __restrict__ bih1, const float* __restrict__ bhh1,
               const float* __restrict__ Wih2, const float* __restrict__ Whh2,
               const float* __restrict__ bih2, const float* __restrict__ bhh2,
               float* __restrict__ out, char* __restrict__ wsb,
               int it_begin, int it_end, int coop)
{
    __shared__ unsigned short Al[32*KP];   // [batch][k] bf16, swizzled
    __shared__ float gl[128*33];           // gate exchange (wave-local rows)
    __shared__ float bias[128];
    __shared__ int lenl[32];

    const int tid = threadIdx.x;
    const int bid = blockIdx.x;
    const int mc  = bid & 7;               // batch chunk
    const int lbi = bid >> 3;              // 0..17 within chunk
    const bool l1 = lbi < LB1;
    const int ub  = (l1 ? lbi : lbi - LB1) * 32;   // unit base
    const int Hl  = l1 ? H1 : H2;

    unsigned short* h1s = (unsigned short*)(wsb + WS_H1);
    unsigned short* h2s = (unsigned short*)(wsb + WS_H2);
    float* c1 = (float*)(wsb + WS_C1);
    float* c2 = (float*)(wsb + WS_C2);
    int* flg = (int*)(wsb + WS_FLG + mc*128);

    const int wave = tid >> 6, lane = tid & 63;
    const int fr = lane & 15, fg = lane >> 4;
    const int sw = fr & 7;

    // ---- weights -> VGPR, once. Row r = wave*16+fr = 4*u_local + gate.
    //      k layout: k<256 = recurrent/o1 part, k in [256,556) = x/h2 part.
    short8 wreg[18];
    {
        const int row = wave*16 + fr;
        const int u = row >> 2, g = row & 3;
        const int unit = ub + u;
        const bool vr = unit < Hl;                 // L2 block 9 pad units
        const long grow = (long)g*Hl + unit;
        #pragma unroll
        for (int ks = 0; ks < 18; ++ks){
            unsigned short v8[8];
            #pragma unroll
            for (int j = 0; j < 8; ++j){
                int k = ks*32 + fg*8 + j;
                float v = 0.0f;
                if (vr && k < K1){
                    if (l1) v = (k < H1) ? Whh1[grow*H1 + k] : Wih1[grow*DIN + (k - H1)];
                    else    v = (k < H1) ? Wih2[grow*H1 + k] : Whh2[grow*H2 + (k - H1)];
                }
                v8[j] = f2bf(v);
            }
            wreg[ks] = *(short8*)v8;
        }
    }
    if (tid < 128){
        int u = tid >> 2, g = tid & 3, unit = ub + u;
        bias[tid] = (unit < Hl)
            ? ((l1?bih1:bih2)[g*Hl+unit] + (l1?bhh1:bhh2)[g*Hl+unit]) : 0.0f;
    }
    if (tid < 32) lenl[tid] = (tid < BQC) ? lengths[mc*BQC + tid] : 0;

    const unsigned short* arow0 = &Al[fr*KP];
    const unsigned short* arow1 = &Al[(16+fr)*KP];
    const int bg_e = mc*BQC + lane;        // epilogue batch (lane<BQC valid)
    const int unit4 = ub + wave*4;         // epilogue/publish unit group

    float creg[4] = {0.f, 0.f, 0.f, 0.f};
    if (!coop && lane < 32){
        float* cs = l1 ? c1 : c2;
        #pragma unroll
        for (int i2 = 0; i2 < 4; ++i2) creg[i2] = cs[(unit4 + i2)*BQ + bg_e];
    }

    __syncthreads();

    for (int it = it_begin; it < it_end; ++it){
        const bool active = l1 ? (it < TSEQ) : (it >= 1);
        const int t = l1 ? it : it - 1;

        if (l1){
            if (active){
                // ---- stage x panel (k 256..575), cached loads ----
                #pragma unroll
                for (int i = 0; i < 3; ++i){
                    int e = tid + i*512;
                    if (e < 1280){
                        int bl = e/40, kcx = 32 + e - (e/40)*40;     // kcx 32..71
                        U16B v; v.u[0] = 0; v.u[1] = 0;
                        if (bl < BQC && kcx <= 69){
                            int bg = mc*BQC + bl;
                            const float* xp = x + ((size_t)bg*TSEQ + t)*DIN + (kcx*8 - 256);
                            float4 f0 = *(const float4*)xp;
                            v.us[0]=f2bf(f0.x); v.us[1]=f2bf(f0.y); v.us[2]=f2bf(f0.z); v.us[3]=f2bf(f0.w);
                            if (kcx <= 68){
                                float4 f1 = *(const float4*)(xp + 4);
                                v.us[4]=f2bf(f1.x); v.us[5]=f2bf(f1.y); v.us[6]=f2bf(f1.z); v.us[7]=f2bf(f1.w);
                            }
                        }
                        *(short8*)&Al[bl*KP + ((kcx ^ (bl&7))<<3)] = v.s8;
                    }
                }
                // ---- FUSED per-lane poll + state load (no B0 on L1 blocks):
                //      lane's producer block = kc0>>2; loads issue the moment
                //      that one flag lands (load RTT overlaps detect skew).
                const int kc0 = tid & 31;
                const int bl0 = tid >> 5, bl1 = bl0 + 16;
                if (coop && it > it_begin){
                    const int* fp = &flg[kc0 >> 2];
                    while (ldflag(fp) < it) __builtin_amdgcn_s_sleep(1);
                    asm volatile("" ::: "memory");     // no load hoist above poll
                }
                const unsigned short* h1p = h1s + (it % 3)*H1SLOT;   // h1(it-1)
                u64 a0, a1, a2 = 0, a3 = 0;
                {
                    const unsigned short* hp = h1p + (size_t)(mc*BQC + bl0)*H1P + kc0*8;
                    a0 = ld8c(hp); a1 = ld8c(hp + 4);                // bl0 < 16 < BQC
                }
                if (bl1 < BQC){
                    const unsigned short* hp = h1p + (size_t)(mc*BQC + bl1)*H1P + kc0*8;
                    a2 = ld8c(hp); a3 = ld8c(hp + 4);
                }
                U16B w0; w0.u[0] = a0; w0.u[1] = a1;
                U16B w1; w1.u[0] = a2; w1.u[1] = a3;
                *(short8*)&Al[bl0*KP + ((kc0 ^ (bl0&7))<<3)] = w0.s8;
                *(short8*)&Al[bl1*KP + ((kc0 ^ (bl1&7))<<3)] = w1.s8;
                // ---- WAR side-poll: L2 o1-readers of the slot we publish
                //      into at this iter finished (L2 flags >= it-1; 1-iter
                //      slack). Ordered before publishes by B1.
                if (coop && tid < 10 && it >= 2){
                    while (ldflag(&flg[8 + tid]) < it - 1) __builtin_amdgcn_s_sleep(1);
                }
            }
        } else {
            // ---- L2: r9 structure. Poll all 18 flags >= it, then B0. ----
            if (coop && it > it_begin && tid < LBT){
                if (active){
                    while (ldflag(&flg[tid]) < it) __builtin_amdgcn_s_sleep(1);
                }
            }
            __syncthreads();   // B0 (L2 blocks only)
            if (active){
                const unsigned short* h1p = h1s + (it % 3)*H1SLOT;       // o1 source
                const unsigned short* h2p = h2s + ((it + 2) % 3)*H2SLOT; // h2(it-1)
                u64 sv[10];
                #pragma unroll
                for (int i = 0; i < 5; ++i){
                    int e = tid + i*512;
                    u64 a = 0, b = 0;
                    if (e < 2304){
                        int bl = e/72, kc = e - (e/72)*72;
                        if (bl < BQC && kc < 70){
                            int bg = mc*BQC + bl;
                            if (kc < 32){                    // o1 = masked h1
                                if (t < lenl[bl]){
                                    const unsigned short* hp = h1p + (size_t)bg*H1P + kc*8;
                                    a = ld8c(hp); b = ld8c(hp + 4);
                                }
                            } else {                         // h2 (kc=69 hits zero pad)
                                const unsigned short* hp = h2p + (size_t)bg*H2P + (kc*8 - 256);
                                a = ld8c(hp); b = ld8c(hp + 4);
                            }
                        }
                    }
                    sv[2*i] = a; sv[2*i+1] = b;
                }
                #pragma unroll
                for (int i = 0; i < 5; ++i){
                    int e = tid + i*512;
                    if (e < 2304){
                        int bl = e/72, kc = e - (e/72)*72;
                        U16B v; v.u[0] = sv[2*i]; v.u[1] = sv[2*i+1];
                        *(short8*)&Al[bl*KP + ((kc ^ (bl&7))<<3)] = v.s8;
                    }
                }
            }
        }
        __syncthreads();   // B1: panel staged; L1 polls joined (all 8 flags >= it)

        if (active){
            // ---- 18 k-step MFMA, weights in VGPR ----
            f32x4 acc0 = {0.f,0.f,0.f,0.f}, acc1 = {0.f,0.f,0.f,0.f};
            #pragma unroll
            for (int ks = 0; ks < 18; ++ks){
                const int off = ((ks*4 + fg) ^ sw) << 3;
                short8 b0 = *(const short8*)(arow0 + off);
                short8 b1 = *(const short8*)(arow1 + off);
                acc0 = __builtin_amdgcn_mfma_f32_16x16x32_bf16(wreg[ks], b0, acc0, 0, 0, 0);
                acc1 = __builtin_amdgcn_mfma_f32_16x16x32_bf16(wreg[ks], b1, acc1, 0, 0, 0);
            }
            // wave-local gate exchange: wave w owns rows 16w..16w+15 entirely;
            // same-wave LDS ops are processed in order -> no barrier needed.
            const int gr = wave*16 + fg*4;
            #pragma unroll
            for (int q = 0; q < 4; ++q){
                gl[(gr+q)*33 + fr]      = acc0[q];
                gl[(gr+q)*33 + 16 + fr] = acc1[q];
            }
            // ---- epilogue: lane b -> units ub+4*wave+0..3, batch b ----
            if (lane < 32){
                float hv[4]; unsigned short hb[4];
                #pragma unroll
                for (int i2 = 0; i2 < 4; ++i2){
                    const int r = wave*16 + i2*4;
                    float gi = gl[(r+0)*33 + lane] + bias[r+0];
                    float gf = gl[(r+1)*33 + lane] + bias[r+1];
                    float gg = gl[(r+2)*33 + lane] + bias[r+2];
                    float go = gl[(r+3)*33 + lane] + bias[r+3];
                    float iv = sigf(gi), fv = sigf(gf), cv = tanhf_(gg), ov = sigf(go);
                    float c = fmaf(fv, creg[i2], iv*cv); creg[i2] = c;
                    hv[i2] = ov * tanhf_(c);
                    hb[i2] = f2bf(hv[i2]);
                }
                if (lane < BQC){
                    U8B pv; pv.us[0]=hb[0]; pv.us[1]=hb[1]; pv.us[2]=hb[2]; pv.us[3]=hb[3];
                    if (l1){
                        pub8((u64*)&h1s[((it+1)%3)*H1SLOT + (size_t)bg_e*H1P + unit4], pv.u);
                        if (it == lenl[lane] - 1){           // h_value (fp32 h)
                            float4 q; q.x=hv[0]; q.y=hv[1]; q.z=hv[2]; q.w=hv[3];
                            *(float4*)(out + 30000000 + (size_t)bg_e*H1 + unit4) = q;
                        }
                    } else if (unit4 < H2){
                        pub8((u64*)&h2s[(it%3)*H2SLOT + (size_t)bg_e*H2P + unit4], pv.u);
                        float4 q; q.x=hv[0]; q.y=hv[1]; q.z=hv[2]; q.w=hv[3];
                        *(float4*)(out + (size_t)bg_e*150000 + (size_t)t*300 + unit4) = q;
                    }
                }
            }
        }

        // ---- B2 (full): drains all waves' returning swaps (APPLIED at the
        //      coherence point) before tid0's posted flag. ----
        __syncthreads();
        if (coop && tid == 0)
            stflag(&flg[lbi], it + 1);
    }

    if (!coop && lane < 32){
        float* cs = l1 ? c1 : c2;
        #pragma unroll
        for (int i2 = 0; i2 < 4; ++i2) cs[(unit4 + i2)*BQ + bg_e] = creg[i2];
    }
}

extern "C" void kernel_launch(void* const* d_in, const int* in_sizes, int n_in,
                              void* d_out, int out_size, void* d_ws, size_t ws_size,
                              hipStream_t stream) {
    const float* x    = (const float*)d_in[0];
    const int*   lens = (const int*)  d_in[1];
    const float* Wih1 = (const float*)d_in[2];
    const float* Whh1 = (const float*)d_in[3];
    const float* bih1 = (const float*)d_in[4];
    const float* bhh1 = (const float*)d_in[5];
    const float* Wih2 = (const float*)d_in[6];
    const float* Whh2 = (const float*)d_in[7];
    const float* bih2 = (const float*)d_in[8];
    const float* bhh2 = (const float*)d_in[9];
    float* out = (float*)d_out;
    char*  ws  = (char*)d_ws;

    // zero state slots (incl. pad), flags, fallback c -- every call (deterministic)
    hipMemsetAsync(d_ws, 0, (size_t)WS_MSET, stream);

    int ib = 0, ie = TSEQ + 1, coop = 1;
    void* args[] = {(void*)&x, (void*)&lens, (void*)&Wih1, (void*)&Whh1, (void*)&bih1, (void*)&bhh1,
                    (void*)&Wih2, (void*)&Whh2, (void*)&bih2, (void*)&bhh2,
                    (void*)&out, (void*)&ws, (void*)&ib, (void*)&ie, (void*)&coop};
    hipError_t err = hipLaunchCooperativeKernel((const void*)lstm_mfma, dim3(NBLK), dim3(512),
                                                args, 0, stream);
    if (err != hipSuccess) {
        (void)hipGetLastError();   // fall back: one launch per iteration (state in ws)
        for (int it = 0; it <= TSEQ; ++it) {
            hipLaunchKernelGGL(lstm_mfma, dim3(NBLK), dim3(512), 0, stream,
                               x, lens, Wih1, Whh1, bih1, bhh1, Wih2, Whh2, bih2, bhh2,
                               out, ws, it, it + 1, 0);
        }
    }
}